// Round 7
// baseline (563.534 us; speedup 1.0000x reference)
//
#include <hip/hip_runtime.h>
#include <hip/hip_bf16.h>
#include <string.h>

#define NN 50000
#define NE 800000
#define DIN 128
#define DH 256
#define NG 64
#define PSPLIT 32

typedef short bf16x8 __attribute__((ext_vector_type(8)));
typedef float f32x4 __attribute__((ext_vector_type(4)));

__device__ __forceinline__ float bf2f(__hip_bfloat16 v) { return __bfloat162float(v); }
__device__ __forceinline__ float bfbits(unsigned int lo16) {
  unsigned int u = lo16 << 16;
  float f;
  memcpy(&f, &u, 4);
  return f;
}
__device__ __forceinline__ unsigned int packbf2(float x, float y) {
  __hip_bfloat16 bx = __float2bfloat16(x), by = __float2bfloat16(y);
  unsigned short ux, uy;
  memcpy(&ux, &bx, 2);
  memcpy(&uy, &by, 2);
  return (unsigned int)ux | ((unsigned int)uy << 16);
}

// flag-driven generic accessors: fbf=1 -> floats stored as bf16; i64=1 -> ints stored as int64
__device__ __forceinline__ float loadF(const void* p, long i, int fbf) {
  return fbf ? bf2f(((const __hip_bfloat16*)p)[i]) : ((const float*)p)[i];
}
__device__ __forceinline__ void storeF(void* p, long i, float v, int fbf) {
  if (fbf) ((__hip_bfloat16*)p)[i] = __float2bfloat16(v);
  else ((float*)p)[i] = v;
}
__device__ __forceinline__ int loadI(const void* p, long i, int i64) {
  return i64 ? (int)((const long long*)p)[i] : ((const int*)p)[i];
}

__global__ void k_detect(const void* x, const void* ei, int* flags) {
  __shared__ int s_f32sig, s_i32sig;
  if (threadIdx.x == 0) { s_f32sig = 0; s_i32sig = 0; }
  __syncthreads();
  int t = threadIdx.x;
  const unsigned short* u = (const unsigned short*)x;
  int f = 0;
  for (int i = 2 * t; i < 8192; i += 512) if (u[i] >= 0x4000) f = 1;
  const unsigned int* w = (const unsigned int*)ei;
  int g = 0;
  for (int i = 2 * t + 1; i < 8192; i += 512) if (w[i] != 0u) g = 1;
  if (f) atomicOr(&s_f32sig, 1);
  if (g) atomicOr(&s_i32sig, 1);
  __syncthreads();
  if (t == 0) { flags[0] = s_f32sig ? 0 : 1; flags[1] = s_i32sig ? 0 : 1; }
}

__global__ void k_zero(int* __restrict__ p, int n) {
  int i = blockIdx.x * blockDim.x + threadIdx.x;
  int stride = gridDim.x * blockDim.x;
  for (; i < n; i += stride) p[i] = 0;
}

// fused: colsum partials + bf16 conversion of x (single pass over x)
__global__ void k_prep(const void* __restrict__ x, __hip_bfloat16* __restrict__ xb,
                       float* __restrict__ colsum, const int* __restrict__ flags) {
  int fbf = flags[0];
  int col = threadIdx.x;  // 0..127
  float acc = 0.f;
  for (int r = blockIdx.x; r < NN; r += gridDim.x) {
    float v = loadF(x, (long)r * DIN + col, fbf);
    acc += v;
    xb[(long)r * DIN + col] = __float2bfloat16(v);
  }
  atomicAdd(&colsum[col], acc);
}

__global__ void k_handcrafted(const float* __restrict__ colsum, void* __restrict__ out,
                              const int* __restrict__ flags) {
  __shared__ float s[DIN];
  int fbf = flags[0];
  int t = threadIdx.x;
  s[t] = colsum[t];
  __syncthreads();
  for (int off = DIN / 2; off > 0; off >>= 1) {
    if (t < off) s[t] += s[t + off];
    __syncthreads();
  }
  float g = s[0];
  storeF(out, NG * DH + t, colsum[t] / g, fbf);
  if (t == 0) storeF(out, NG * DH + DIN, logf(g), fbf);
}

// pack weights into MFMA b-frag order:
// pack[m*K*DH + ((ct*KS + ks)*64 + l)*8 + j] = W_m[(ks*32 + (l>>4)*8 + j)*DH + ct*16 + (l&15)]
__global__ void k_pack_w(const void* __restrict__ Wrel, const void* __restrict__ Wroot,
                         const void* __restrict__ bias, __hip_bfloat16* __restrict__ pack,
                         float* __restrict__ biasf, const int* __restrict__ flags, int K) {
  int fbf = flags[0];
  int KS = K >> 5;
  int total = 2 * K * DH;
  int i = blockIdx.x * blockDim.x + threadIdx.x;
  int stride = gridDim.x * blockDim.x;
  for (int p = i; p < total; p += stride) {
    int m = p / (K * DH);
    int r = p % (K * DH);
    int j = r & 7;
    int l = (r >> 3) & 63;
    int q2 = r >> 9;       // ct*KS + ks
    int ks = q2 % KS;
    int ct = q2 / KS;
    int kk = ks * 32 + (l >> 4) * 8 + j;
    int col = ct * 16 + (l & 15);
    const void* W = m ? Wroot : Wrel;
    pack[p] = __float2bfloat16(loadF(W, (long)kk * DH + col, fbf));
  }
  if (i < DH) biasf[i] = loadF(bias, i, fbf);
}

// ---------- CSR build ----------
__global__ void k_deg(const void* __restrict__ ei, int* __restrict__ cnt,
                      const int* __restrict__ flags) {
  int i64 = flags[1];
  int e = blockIdx.x * blockDim.x + threadIdx.x;
  int stride = gridDim.x * blockDim.x;
  for (; e < NE; e += stride) {
    int d = loadI(ei, (long)NE + e, i64);
    d = min(max(d, 0), NN - 1);
    atomicAdd(&cnt[d], 1);
  }
}

#define SCAN_B 256
__global__ void k_scan1(const int* __restrict__ cnt, int* __restrict__ rowptr,
                        int* __restrict__ bsum) {
  __shared__ int s[SCAN_B];
  int b = blockIdx.x, t = threadIdx.x;
  int i = b * SCAN_B + t;
  int v = (i < NN) ? cnt[i] : 0;
  s[t] = v;
  __syncthreads();
  for (int off = 1; off < SCAN_B; off <<= 1) {
    int xv = (t >= off) ? s[t - off] : 0;
    __syncthreads();
    s[t] += xv;
    __syncthreads();
  }
  if (i < NN) rowptr[i] = s[t] - v;
  if (t == SCAN_B - 1) bsum[b] = s[t];
}

__global__ void k_scan2(int* __restrict__ bsum, int nb) {
  __shared__ int s[SCAN_B];
  int t = threadIdx.x;
  int v = (t < nb) ? bsum[t] : 0;
  s[t] = v;
  __syncthreads();
  for (int off = 1; off < SCAN_B; off <<= 1) {
    int xv = (t >= off) ? s[t - off] : 0;
    __syncthreads();
    s[t] += xv;
    __syncthreads();
  }
  if (t < nb) bsum[t] = s[t] - v;  // exclusive
}

__global__ void k_scan3(int* __restrict__ rowptr, const int* __restrict__ bsum) {
  int i = blockIdx.x * blockDim.x + threadIdx.x;
  int stride = gridDim.x * blockDim.x;
  for (; i < NN; i += stride) rowptr[i] += bsum[i >> 8];
  if (blockIdx.x == 0 && threadIdx.x == 0) rowptr[NN] = NE;
}

__global__ void k_fill(const void* __restrict__ ei, const int* __restrict__ rowptr,
                       int* __restrict__ cur, int* __restrict__ srcs,
                       const int* __restrict__ flags) {
  int i64 = flags[1];
  int e = blockIdx.x * blockDim.x + threadIdx.x;
  int stride = gridDim.x * blockDim.x;
  for (; e < NE; e += stride) {
    int s = loadI(ei, e, i64);
    int d = loadI(ei, (long)NE + e, i64);
    s = min(max(s, 0), NN - 1);
    d = min(max(d, 0), NN - 1);
    int p = atomicAdd(&cur[d], 1);
    srcs[rowptr[d] + p] = s;
  }
}

// ---------- gathers: one wave per node, whole row per wave-instruction ----------
// D=256: lane loads uint2 (8B = 4 bf16); 64 lanes * 8B = 512B row; 4 rows in flight
__global__ __launch_bounds__(256) void k_gather256(
    const int* __restrict__ rowptr, const int* __restrict__ srcs,
    const __hip_bfloat16* __restrict__ h, __hip_bfloat16* __restrict__ agg) {
  int node = blockIdx.x * 4 + (threadIdx.x >> 6);
  if (node >= NN) return;
  int lane = threadIdx.x & 63;
  int beg = rowptr[node], end = rowptr[node + 1];
  const uint2* h2 = (const uint2*)h;  // 64 uint2 per row
  float a0 = 0.f, a1 = 0.f, a2 = 0.f, a3 = 0.f;
  int i = beg;
  for (; i + 3 < end; i += 4) {
    int s0 = srcs[i] * 64 + lane;
    int s1 = srcs[i + 1] * 64 + lane;
    int s2 = srcs[i + 2] * 64 + lane;
    int s3 = srcs[i + 3] * 64 + lane;
    uint2 v0 = h2[s0];
    uint2 v1 = h2[s1];
    uint2 v2 = h2[s2];
    uint2 v3 = h2[s3];
    a0 += bfbits(v0.x & 0xffffu) + bfbits(v1.x & 0xffffu) + bfbits(v2.x & 0xffffu) + bfbits(v3.x & 0xffffu);
    a1 += bfbits(v0.x >> 16) + bfbits(v1.x >> 16) + bfbits(v2.x >> 16) + bfbits(v3.x >> 16);
    a2 += bfbits(v0.y & 0xffffu) + bfbits(v1.y & 0xffffu) + bfbits(v2.y & 0xffffu) + bfbits(v3.y & 0xffffu);
    a3 += bfbits(v0.y >> 16) + bfbits(v1.y >> 16) + bfbits(v2.y >> 16) + bfbits(v3.y >> 16);
  }
  for (; i < end; ++i) {
    uint2 v0 = h2[srcs[i] * 64 + lane];
    a0 += bfbits(v0.x & 0xffffu);
    a1 += bfbits(v0.x >> 16);
    a2 += bfbits(v0.y & 0xffffu);
    a3 += bfbits(v0.y >> 16);
  }
  uint2 o;
  o.x = packbf2(a0, a1);
  o.y = packbf2(a2, a3);
  ((uint2*)agg)[node * 64 + lane] = o;
}

// D=128: lane loads uint (4B = 2 bf16); 64 lanes * 4B = 256B row; 4 rows in flight
__global__ __launch_bounds__(256) void k_gather128(
    const int* __restrict__ rowptr, const int* __restrict__ srcs,
    const __hip_bfloat16* __restrict__ h, __hip_bfloat16* __restrict__ agg) {
  int node = blockIdx.x * 4 + (threadIdx.x >> 6);
  if (node >= NN) return;
  int lane = threadIdx.x & 63;
  int beg = rowptr[node], end = rowptr[node + 1];
  const unsigned int* h2 = (const unsigned int*)h;  // 64 uints per row
  float a0 = 0.f, a1 = 0.f;
  int i = beg;
  for (; i + 3 < end; i += 4) {
    unsigned int v0 = h2[srcs[i] * 64 + lane];
    unsigned int v1 = h2[srcs[i + 1] * 64 + lane];
    unsigned int v2 = h2[srcs[i + 2] * 64 + lane];
    unsigned int v3 = h2[srcs[i + 3] * 64 + lane];
    a0 += bfbits(v0 & 0xffffu) + bfbits(v1 & 0xffffu) + bfbits(v2 & 0xffffu) + bfbits(v3 & 0xffffu);
    a1 += bfbits(v0 >> 16) + bfbits(v1 >> 16) + bfbits(v2 >> 16) + bfbits(v3 >> 16);
  }
  for (; i < end; ++i) {
    unsigned int v0 = h2[srcs[i] * 64 + lane];
    a0 += bfbits(v0 & 0xffffu);
    a1 += bfbits(v0 >> 16);
  }
  ((unsigned int*)agg)[node * 64 + lane] = packbf2(a0, a1);
}

// out[n][:] = relu(A1[n][:] @ Wrel + A2[n][:] @ Wroot + bias)
// grid (M/64, 2): block = 64 rows x 128 cols; 4 waves, each 64x32 (mt=4, ct=2)
// acc = 32 VGPRs/wave (vs 64 before) -> ~5 waves/SIMD occupancy
__global__ __launch_bounds__(256) void k_gemm(
    const __hip_bfloat16* __restrict__ A1, const __hip_bfloat16* __restrict__ A2,
    const __hip_bfloat16* __restrict__ Wpack, const float* __restrict__ bias,
    __hip_bfloat16* __restrict__ out, int K) {
  int KS = K >> 5;
  int lane = threadIdx.x & 63;
  int wave = threadIdx.x >> 6;
  int m15 = lane & 15;
  int q = lane >> 4;
  int row0 = blockIdx.x * 64;
  int cy = blockIdx.y;  // col half: 0 or 1
  const short* A1s = (const short*)A1;
  const short* A2s = (const short*)A2;
  const short* Wp = (const short*)Wpack;
  int wrootOfs = K * DH;  // elems: second packed matrix
  f32x4 acc[4][2] = {};
  for (int ks = 0; ks < KS; ++ks) {
    int kofs = ks * 32 + q * 8;
    bf16x8 a1[4], a2[4], b1[2], b2[2];
#pragma unroll
    for (int mt = 0; mt < 4; ++mt) {
      int r = row0 + mt * 16 + m15;
      if (r > NN - 1) r = NN - 1;
      a1[mt] = *(const bf16x8*)(A1s + r * K + kofs);
      a2[mt] = *(const bf16x8*)(A2s + r * K + kofs);
    }
#pragma unroll
    for (int ct = 0; ct < 2; ++ct) {
      int gct = cy * 8 + wave * 2 + ct;
      const short* base = Wp + ((gct * KS + ks) * 64 + lane) * 8;
      b1[ct] = *(const bf16x8*)(base);
      b2[ct] = *(const bf16x8*)(base + wrootOfs);
    }
#pragma unroll
    for (int mt = 0; mt < 4; ++mt)
#pragma unroll
      for (int ct = 0; ct < 2; ++ct) {
        acc[mt][ct] = __builtin_amdgcn_mfma_f32_16x16x32_bf16(a1[mt], b1[ct], acc[mt][ct], 0, 0, 0);
        acc[mt][ct] = __builtin_amdgcn_mfma_f32_16x16x32_bf16(a2[mt], b2[ct], acc[mt][ct], 0, 0, 0);
      }
  }
#pragma unroll
  for (int mt = 0; mt < 4; ++mt)
#pragma unroll
    for (int ct = 0; ct < 2; ++ct) {
      int col = (cy * 8 + wave * 2 + ct) * 16 + m15;
      float bv = bias[col];
#pragma unroll
      for (int r = 0; r < 4; ++r) {
        int row = row0 + mt * 16 + q * 4 + r;
        if (row < NN) {
          float v = acc[mt][ct][r] + bv;
          out[row * DH + col] = __float2bfloat16(fmaxf(v, 0.f));
        }
      }
    }
}

// ---------- pooling (batch is sorted -> segment bounds, no big atomics) ----------
__global__ void k_bounds(const void* __restrict__ batch, int* __restrict__ gstart,
                         int* __restrict__ gend, const int* __restrict__ flags) {
  int i64 = flags[1];
  int n = blockIdx.x * blockDim.x + threadIdx.x;
  if (n >= NN) return;
  int b = min(max(loadI(batch, n, i64), 0), NG - 1);
  int bp = (n == 0) ? -1 : min(max(loadI(batch, n - 1, i64), 0), NG - 1);
  if (b != bp) gstart[b] = n;
  int bn = (n == NN - 1) ? -1 : min(max(loadI(batch, n + 1, i64), 0), NG - 1);
  if (b != bn) gend[b] = n + 1;
}

// grid (NG, PSPLIT), block 128: each block partial-sums a slice of the graph's rows
__global__ void k_poolpart(const int* __restrict__ gstart, const int* __restrict__ gend,
                           const __hip_bfloat16* __restrict__ h, float* __restrict__ pooled) {
  int g = blockIdx.x;
  int p = blockIdx.y;
  int j = threadIdx.x;  // 0..127, 2 cols each
  int s = gstart[g], e = gend[g];
  int len = e - s;
  if (len <= 0) return;
  int chunk = (len + PSPLIT - 1) / PSPLIT;
  int rs = s + p * chunk;
  int re = min(rs + chunk, e);
  if (rs >= re) return;
  const unsigned int* h2 = (const unsigned int*)h;  // 128 uints per row
  float a0 = 0.f, a1 = 0.f;
  for (int r = rs; r < re; ++r) {
    unsigned int v = h2[(long)r * 128 + j];
    a0 += bfbits(v & 0xffffu);
    a1 += bfbits(v >> 16);
  }
  atomicAdd(&pooled[g * DH + 2 * j], a0);
  atomicAdd(&pooled[g * DH + 2 * j + 1], a1);
}

__global__ void k_poolfin(const int* __restrict__ gstart, const int* __restrict__ gend,
                          const float* __restrict__ pooled, void* __restrict__ out,
                          const int* __restrict__ flags) {
  int fbf = flags[0];
  int g = blockIdx.x;
  int j = threadIdx.x;
  float cnt = fmaxf((float)(gend[g] - gstart[g]), 1.0f);
  storeF(out, (long)g * DH + j, pooled[g * DH + j] / cnt, fbf);
}

extern "C" void kernel_launch(void* const* d_in, const int* in_sizes, int n_in,
                              void* d_out, int out_size, void* d_ws, size_t ws_size,
                              hipStream_t stream) {
  const void* x = d_in[0];
  const void* ei = d_in[1];
  const void* batch = d_in[2];
  const void* W1r = d_in[3];
  const void* W1o = d_in[4];
  const void* b1 = d_in[5];
  const void* W2r = d_in[6];
  const void* W2o = d_in[7];
  const void* b2 = d_in[8];
  void* out = d_out;

  // ---- workspace layout (256B-aligned chunks) ----
  char* w = (char*)d_ws;
  auto alloc = [&](size_t bytes) -> char* {
    char* p = w;
    w += (bytes + 255) & ~(size_t)255;
    return p;
  };
  int* flags = (int*)alloc(64);
  // contiguous zero region: cnt, cur, colsum, gstart, gend, pooled
  const int zero_n = NN + NN + DIN + NG + NG + NG * DH;
  int* zreg = (int*)alloc((size_t)zero_n * 4);
  int* cnt = zreg;
  int* cur = cnt + NN;
  float* colsum = (float*)(cur + NN);
  int* gstart = (int*)(colsum + DIN);
  int* gend = gstart + NG;
  float* pooled = (float*)(gend + NG);
  int* rowptr = (int*)alloc((NN + 1) * 4);
  int* bsum = (int*)alloc(SCAN_B * 4);
  int* srcs = (int*)alloc((size_t)NE * 4);
  __hip_bfloat16* xb = (__hip_bfloat16*)alloc((size_t)NN * DIN * 2);
  __hip_bfloat16* aggb = (__hip_bfloat16*)alloc((size_t)NN * DH * 2);
  __hip_bfloat16* hA = (__hip_bfloat16*)alloc((size_t)NN * DH * 2);
  __hip_bfloat16* hB = (__hip_bfloat16*)alloc((size_t)NN * DH * 2);
  __hip_bfloat16* wp1 = (__hip_bfloat16*)alloc((size_t)2 * DIN * DH * 2);
  __hip_bfloat16* wp2 = (__hip_bfloat16*)alloc((size_t)2 * DH * DH * 2);
  float* b1f = (float*)alloc(DH * 4);
  float* b2f = (float*)alloc(DH * 4);

  const int nblk = (NN + SCAN_B - 1) / SCAN_B;       // 196
  const dim3 gemm_grid((NN + 63) / 64, 2);           // 782 x 2
  const int gat_grid = (NN + 3) / 4;                 // 12500

  k_detect<<<1, 256, 0, stream>>>(x, ei, flags);
  k_zero<<<512, 256, 0, stream>>>(zreg, zero_n);

  // weight packing + fused colsum/convert + handcrafted head
  k_pack_w<<<64, 256, 0, stream>>>(W1r, W1o, b1, wp1, b1f, flags, DIN);
  k_pack_w<<<128, 256, 0, stream>>>(W2r, W2o, b2, wp2, b2f, flags, DH);
  k_prep<<<512, 128, 0, stream>>>(x, xb, colsum, flags);
  k_handcrafted<<<1, 128, 0, stream>>>(colsum, out, flags);

  // CSR build (once; reused by all 3 layers)
  k_deg<<<1024, 256, 0, stream>>>(ei, cnt, flags);
  k_scan1<<<nblk, SCAN_B, 0, stream>>>(cnt, rowptr, bsum);
  k_scan2<<<1, SCAN_B, 0, stream>>>(bsum, nblk);
  k_scan3<<<256, 256, 0, stream>>>(rowptr, bsum);
  k_fill<<<1024, 256, 0, stream>>>(ei, rowptr, cur, srcs, flags);

  // layer 1 (K = 128): xb -> hA
  k_gather128<<<gat_grid, 256, 0, stream>>>(rowptr, srcs, xb, aggb);
  k_gemm<<<gemm_grid, 256, 0, stream>>>(aggb, xb, wp1, b1f, hA, DIN);
  // layer 2 (K = 256): hA -> hB (ping-pong, no aliasing)
  k_gather256<<<gat_grid, 256, 0, stream>>>(rowptr, srcs, hA, aggb);
  k_gemm<<<gemm_grid, 256, 0, stream>>>(aggb, hA, wp2, b2f, hB, DH);
  // layer 3 (K = 256, shared weights): hB -> hA
  k_gather256<<<gat_grid, 256, 0, stream>>>(rowptr, srcs, hB, aggb);
  k_gemm<<<gemm_grid, 256, 0, stream>>>(aggb, hB, wp2, b2f, hA, DH);

  // mean pool: segment bounds (batch sorted) + split partial sums + finalize
  k_bounds<<<nblk, 256, 0, stream>>>(batch, gstart, gend, flags);
  k_poolpart<<<dim3(NG, PSPLIT), 128, 0, stream>>>(gstart, gend, hA, pooled);
  k_poolfin<<<NG, DH, 0, stream>>>(gstart, gend, pooled, out, flags);
}

// Round 8
// 507.211 us; speedup vs baseline: 1.1110x; 1.1110x over previous
//
#include <hip/hip_runtime.h>
#include <hip/hip_bf16.h>
#include <string.h>

#define NN 50000
#define NE 800000
#define DIN 128
#define DH 256
#define NG 64
#define PSPLIT 32

typedef short bf16x8 __attribute__((ext_vector_type(8)));
typedef float f32x4 __attribute__((ext_vector_type(4)));

__device__ __forceinline__ float bf2f(__hip_bfloat16 v) { return __bfloat162float(v); }
__device__ __forceinline__ float bfbits(unsigned int lo16) {
  unsigned int u = lo16 << 16;
  float f;
  memcpy(&f, &u, 4);
  return f;
}
__device__ __forceinline__ unsigned int packbf2(float x, float y) {
  __hip_bfloat16 bx = __float2bfloat16(x), by = __float2bfloat16(y);
  unsigned short ux, uy;
  memcpy(&ux, &bx, 2);
  memcpy(&uy, &by, 2);
  return (unsigned int)ux | ((unsigned int)uy << 16);
}

// flag-driven generic accessors: fbf=1 -> floats stored as bf16; i64=1 -> ints stored as int64
__device__ __forceinline__ float loadF(const void* p, long i, int fbf) {
  return fbf ? bf2f(((const __hip_bfloat16*)p)[i]) : ((const float*)p)[i];
}
__device__ __forceinline__ void storeF(void* p, long i, float v, int fbf) {
  if (fbf) ((__hip_bfloat16*)p)[i] = __float2bfloat16(v);
  else ((float*)p)[i] = v;
}
__device__ __forceinline__ int loadI(const void* p, long i, int i64) {
  return i64 ? (int)((const long long*)p)[i] : ((const int*)p)[i];
}

__global__ void k_detect(const void* x, const void* ei, int* flags) {
  __shared__ int s_f32sig, s_i32sig;
  if (threadIdx.x == 0) { s_f32sig = 0; s_i32sig = 0; }
  __syncthreads();
  int t = threadIdx.x;
  const unsigned short* u = (const unsigned short*)x;
  int f = 0;
  for (int i = 2 * t; i < 8192; i += 512) if (u[i] >= 0x4000) f = 1;
  const unsigned int* w = (const unsigned int*)ei;
  int g = 0;
  for (int i = 2 * t + 1; i < 8192; i += 512) if (w[i] != 0u) g = 1;
  if (f) atomicOr(&s_f32sig, 1);
  if (g) atomicOr(&s_i32sig, 1);
  __syncthreads();
  if (t == 0) { flags[0] = s_f32sig ? 0 : 1; flags[1] = s_i32sig ? 0 : 1; }
}

__global__ void k_zero(int* __restrict__ p, int n) {
  int i = blockIdx.x * blockDim.x + threadIdx.x;
  int stride = gridDim.x * blockDim.x;
  for (; i < n; i += stride) p[i] = 0;
}

// fused: colsum partials + bf16 conversion of x (single pass over x)
__global__ void k_prep(const void* __restrict__ x, __hip_bfloat16* __restrict__ xb,
                       float* __restrict__ colsum, const int* __restrict__ flags) {
  int fbf = flags[0];
  int col = threadIdx.x;  // 0..127
  float acc = 0.f;
  for (int r = blockIdx.x; r < NN; r += gridDim.x) {
    float v = loadF(x, (long)r * DIN + col, fbf);
    acc += v;
    xb[(long)r * DIN + col] = __float2bfloat16(v);
  }
  atomicAdd(&colsum[col], acc);
}

__global__ void k_handcrafted(const float* __restrict__ colsum, void* __restrict__ out,
                              const int* __restrict__ flags) {
  __shared__ float s[DIN];
  int fbf = flags[0];
  int t = threadIdx.x;
  s[t] = colsum[t];
  __syncthreads();
  for (int off = DIN / 2; off > 0; off >>= 1) {
    if (t < off) s[t] += s[t + off];
    __syncthreads();
  }
  float g = s[0];
  storeF(out, NG * DH + t, colsum[t] / g, fbf);
  if (t == 0) storeF(out, NG * DH + DIN, logf(g), fbf);
}

// pack weights into MFMA b-frag order:
// pack[m*K*DH + ((ct*KS + ks)*64 + l)*8 + j] = W_m[(ks*32 + (l>>4)*8 + j)*DH + ct*16 + (l&15)]
__global__ void k_pack_w(const void* __restrict__ Wrel, const void* __restrict__ Wroot,
                         const void* __restrict__ bias, __hip_bfloat16* __restrict__ pack,
                         float* __restrict__ biasf, const int* __restrict__ flags, int K) {
  int fbf = flags[0];
  int KS = K >> 5;
  int total = 2 * K * DH;
  int i = blockIdx.x * blockDim.x + threadIdx.x;
  int stride = gridDim.x * blockDim.x;
  for (int p = i; p < total; p += stride) {
    int m = p / (K * DH);
    int r = p % (K * DH);
    int j = r & 7;
    int l = (r >> 3) & 63;
    int q2 = r >> 9;       // ct*KS + ks
    int ks = q2 % KS;
    int ct = q2 / KS;
    int kk = ks * 32 + (l >> 4) * 8 + j;
    int col = ct * 16 + (l & 15);
    const void* W = m ? Wroot : Wrel;
    pack[p] = __float2bfloat16(loadF(W, (long)kk * DH + col, fbf));
  }
  if (i < DH) biasf[i] = loadF(bias, i, fbf);
}

// ---------- CSR build ----------
__global__ void k_deg(const void* __restrict__ ei, int* __restrict__ cnt,
                      const int* __restrict__ flags) {
  int i64 = flags[1];
  int e = blockIdx.x * blockDim.x + threadIdx.x;
  int stride = gridDim.x * blockDim.x;
  for (; e < NE; e += stride) {
    int d = loadI(ei, (long)NE + e, i64);
    d = min(max(d, 0), NN - 1);
    atomicAdd(&cnt[d], 1);
  }
}

#define SCAN_B 256
__global__ void k_scan1(const int* __restrict__ cnt, int* __restrict__ rowptr,
                        int* __restrict__ bsum) {
  __shared__ int s[SCAN_B];
  int b = blockIdx.x, t = threadIdx.x;
  int i = b * SCAN_B + t;
  int v = (i < NN) ? cnt[i] : 0;
  s[t] = v;
  __syncthreads();
  for (int off = 1; off < SCAN_B; off <<= 1) {
    int xv = (t >= off) ? s[t - off] : 0;
    __syncthreads();
    s[t] += xv;
    __syncthreads();
  }
  if (i < NN) rowptr[i] = s[t] - v;
  if (t == SCAN_B - 1) bsum[b] = s[t];
}

__global__ void k_scan2(int* __restrict__ bsum, int nb) {
  __shared__ int s[SCAN_B];
  int t = threadIdx.x;
  int v = (t < nb) ? bsum[t] : 0;
  s[t] = v;
  __syncthreads();
  for (int off = 1; off < SCAN_B; off <<= 1) {
    int xv = (t >= off) ? s[t - off] : 0;
    __syncthreads();
    s[t] += xv;
    __syncthreads();
  }
  if (t < nb) bsum[t] = s[t] - v;  // exclusive
}

__global__ void k_scan3(int* __restrict__ rowptr, const int* __restrict__ bsum) {
  int i = blockIdx.x * blockDim.x + threadIdx.x;
  int stride = gridDim.x * blockDim.x;
  for (; i < NN; i += stride) rowptr[i] += bsum[i >> 8];
  if (blockIdx.x == 0 && threadIdx.x == 0) rowptr[NN] = NE;
}

__global__ void k_fill(const void* __restrict__ ei, const int* __restrict__ rowptr,
                       int* __restrict__ cur, int* __restrict__ srcs,
                       const int* __restrict__ flags) {
  int i64 = flags[1];
  int e = blockIdx.x * blockDim.x + threadIdx.x;
  int stride = gridDim.x * blockDim.x;
  for (; e < NE; e += stride) {
    int s = loadI(ei, e, i64);
    int d = loadI(ei, (long)NE + e, i64);
    s = min(max(s, 0), NN - 1);
    d = min(max(d, 0), NN - 1);
    int p = atomicAdd(&cur[d], 1);
    srcs[rowptr[d] + p] = s;
  }
}

// ---------- gathers: one wave per node, whole row per wave-instruction ----------
// D=256: lane loads uint2 (8B = 4 bf16); 64 lanes * 8B = 512B row; 4 rows in flight
__global__ __launch_bounds__(256) void k_gather256(
    const int* __restrict__ rowptr, const int* __restrict__ srcs,
    const __hip_bfloat16* __restrict__ h, __hip_bfloat16* __restrict__ agg) {
  int node = blockIdx.x * 4 + (threadIdx.x >> 6);
  if (node >= NN) return;
  int lane = threadIdx.x & 63;
  int beg = rowptr[node], end = rowptr[node + 1];
  const uint2* h2 = (const uint2*)h;  // 64 uint2 per row
  float a0 = 0.f, a1 = 0.f, a2 = 0.f, a3 = 0.f;
  int i = beg;
  for (; i + 3 < end; i += 4) {
    int s0 = srcs[i] * 64 + lane;
    int s1 = srcs[i + 1] * 64 + lane;
    int s2 = srcs[i + 2] * 64 + lane;
    int s3 = srcs[i + 3] * 64 + lane;
    uint2 v0 = h2[s0];
    uint2 v1 = h2[s1];
    uint2 v2 = h2[s2];
    uint2 v3 = h2[s3];
    a0 += bfbits(v0.x & 0xffffu) + bfbits(v1.x & 0xffffu) + bfbits(v2.x & 0xffffu) + bfbits(v3.x & 0xffffu);
    a1 += bfbits(v0.x >> 16) + bfbits(v1.x >> 16) + bfbits(v2.x >> 16) + bfbits(v3.x >> 16);
    a2 += bfbits(v0.y & 0xffffu) + bfbits(v1.y & 0xffffu) + bfbits(v2.y & 0xffffu) + bfbits(v3.y & 0xffffu);
    a3 += bfbits(v0.y >> 16) + bfbits(v1.y >> 16) + bfbits(v2.y >> 16) + bfbits(v3.y >> 16);
  }
  for (; i < end; ++i) {
    uint2 v0 = h2[srcs[i] * 64 + lane];
    a0 += bfbits(v0.x & 0xffffu);
    a1 += bfbits(v0.x >> 16);
    a2 += bfbits(v0.y & 0xffffu);
    a3 += bfbits(v0.y >> 16);
  }
  uint2 o;
  o.x = packbf2(a0, a1);
  o.y = packbf2(a2, a3);
  ((uint2*)agg)[node * 64 + lane] = o;
}

// D=128: lane loads uint (4B = 2 bf16); 64 lanes * 4B = 256B row; 4 rows in flight
__global__ __launch_bounds__(256) void k_gather128(
    const int* __restrict__ rowptr, const int* __restrict__ srcs,
    const __hip_bfloat16* __restrict__ h, __hip_bfloat16* __restrict__ agg) {
  int node = blockIdx.x * 4 + (threadIdx.x >> 6);
  if (node >= NN) return;
  int lane = threadIdx.x & 63;
  int beg = rowptr[node], end = rowptr[node + 1];
  const unsigned int* h2 = (const unsigned int*)h;  // 64 uints per row
  float a0 = 0.f, a1 = 0.f;
  int i = beg;
  for (; i + 3 < end; i += 4) {
    unsigned int v0 = h2[srcs[i] * 64 + lane];
    unsigned int v1 = h2[srcs[i + 1] * 64 + lane];
    unsigned int v2 = h2[srcs[i + 2] * 64 + lane];
    unsigned int v3 = h2[srcs[i + 3] * 64 + lane];
    a0 += bfbits(v0 & 0xffffu) + bfbits(v1 & 0xffffu) + bfbits(v2 & 0xffffu) + bfbits(v3 & 0xffffu);
    a1 += bfbits(v0 >> 16) + bfbits(v1 >> 16) + bfbits(v2 >> 16) + bfbits(v3 >> 16);
  }
  for (; i < end; ++i) {
    unsigned int v0 = h2[srcs[i] * 64 + lane];
    a0 += bfbits(v0 & 0xffffu);
    a1 += bfbits(v0 >> 16);
  }
  ((unsigned int*)agg)[node * 64 + lane] = packbf2(a0, a1);
}

// out[n][:] = relu(A1[n][:] @ Wrel + A2[n][:] @ Wroot + bias)
// block = 32 rows x 256 cols, 4 waves; wave w = 32x64 tile (mt=2, ct=4), full K unrolled.
// A rows are read by exactly ONE block (no cross-XCD duplication); acc = 32 VGPRs.
template <int K>
__global__ __launch_bounds__(256, 4) void k_gemm(
    const __hip_bfloat16* __restrict__ A1, const __hip_bfloat16* __restrict__ A2,
    const __hip_bfloat16* __restrict__ Wpack, const float* __restrict__ bias,
    __hip_bfloat16* __restrict__ out) {
  constexpr int KS = K >> 5;
  int lane = threadIdx.x & 63;
  int wave = threadIdx.x >> 6;
  int m15 = lane & 15;
  int q = lane >> 4;
  int row0 = blockIdx.x * 32;
  const short* A1s = (const short*)A1;
  const short* A2s = (const short*)A2;
  const short* Wp = (const short*)Wpack;
  const int wrootOfs = K * DH;  // elems: second packed matrix
  f32x4 acc[2][4] = {};
#pragma unroll
  for (int ks = 0; ks < KS; ++ks) {
    int kofs = ks * 32 + q * 8;
    bf16x8 a1[2], a2[2], b1[4], b2[4];
#pragma unroll
    for (int mt = 0; mt < 2; ++mt) {
      int r = row0 + mt * 16 + m15;
      if (r > NN - 1) r = NN - 1;
      a1[mt] = *(const bf16x8*)(A1s + r * K + kofs);
      a2[mt] = *(const bf16x8*)(A2s + r * K + kofs);
    }
#pragma unroll
    for (int ct = 0; ct < 4; ++ct) {
      int gct = wave * 4 + ct;
      const short* base = Wp + ((gct * KS + ks) * 64 + lane) * 8;
      b1[ct] = *(const bf16x8*)(base);
      b2[ct] = *(const bf16x8*)(base + wrootOfs);
    }
#pragma unroll
    for (int mt = 0; mt < 2; ++mt)
#pragma unroll
      for (int ct = 0; ct < 4; ++ct) {
        acc[mt][ct] = __builtin_amdgcn_mfma_f32_16x16x32_bf16(a1[mt], b1[ct], acc[mt][ct], 0, 0, 0);
        acc[mt][ct] = __builtin_amdgcn_mfma_f32_16x16x32_bf16(a2[mt], b2[ct], acc[mt][ct], 0, 0, 0);
      }
  }
#pragma unroll
  for (int mt = 0; mt < 2; ++mt)
#pragma unroll
    for (int ct = 0; ct < 4; ++ct) {
      int col = (wave * 4 + ct) * 16 + m15;
      float bv = bias[col];
#pragma unroll
      for (int r = 0; r < 4; ++r) {
        int row = row0 + mt * 16 + q * 4 + r;
        if (row < NN) {
          float v = acc[mt][ct][r] + bv;
          out[row * DH + col] = __float2bfloat16(fmaxf(v, 0.f));
        }
      }
    }
}

// ---------- pooling (batch is sorted -> segment bounds, no big atomics) ----------
__global__ void k_bounds(const void* __restrict__ batch, int* __restrict__ gstart,
                         int* __restrict__ gend, const int* __restrict__ flags) {
  int i64 = flags[1];
  int n = blockIdx.x * blockDim.x + threadIdx.x;
  if (n >= NN) return;
  int b = min(max(loadI(batch, n, i64), 0), NG - 1);
  int bp = (n == 0) ? -1 : min(max(loadI(batch, n - 1, i64), 0), NG - 1);
  if (b != bp) gstart[b] = n;
  int bn = (n == NN - 1) ? -1 : min(max(loadI(batch, n + 1, i64), 0), NG - 1);
  if (b != bn) gend[b] = n + 1;
}

// grid (NG, PSPLIT), block 128: each block partial-sums a slice of the graph's rows
__global__ void k_poolpart(const int* __restrict__ gstart, const int* __restrict__ gend,
                           const __hip_bfloat16* __restrict__ h, float* __restrict__ pooled) {
  int g = blockIdx.x;
  int p = blockIdx.y;
  int j = threadIdx.x;  // 0..127, 2 cols each
  int s = gstart[g], e = gend[g];
  int len = e - s;
  if (len <= 0) return;
  int chunk = (len + PSPLIT - 1) / PSPLIT;
  int rs = s + p * chunk;
  int re = min(rs + chunk, e);
  if (rs >= re) return;
  const unsigned int* h2 = (const unsigned int*)h;  // 128 uints per row
  float a0 = 0.f, a1 = 0.f;
  for (int r = rs; r < re; ++r) {
    unsigned int v = h2[(long)r * 128 + j];
    a0 += bfbits(v & 0xffffu);
    a1 += bfbits(v >> 16);
  }
  atomicAdd(&pooled[g * DH + 2 * j], a0);
  atomicAdd(&pooled[g * DH + 2 * j + 1], a1);
}

__global__ void k_poolfin(const int* __restrict__ gstart, const int* __restrict__ gend,
                          const float* __restrict__ pooled, void* __restrict__ out,
                          const int* __restrict__ flags) {
  int fbf = flags[0];
  int g = blockIdx.x;
  int j = threadIdx.x;
  float cnt = fmaxf((float)(gend[g] - gstart[g]), 1.0f);
  storeF(out, (long)g * DH + j, pooled[g * DH + j] / cnt, fbf);
}

extern "C" void kernel_launch(void* const* d_in, const int* in_sizes, int n_in,
                              void* d_out, int out_size, void* d_ws, size_t ws_size,
                              hipStream_t stream) {
  const void* x = d_in[0];
  const void* ei = d_in[1];
  const void* batch = d_in[2];
  const void* W1r = d_in[3];
  const void* W1o = d_in[4];
  const void* b1 = d_in[5];
  const void* W2r = d_in[6];
  const void* W2o = d_in[7];
  const void* b2 = d_in[8];
  void* out = d_out;

  // ---- workspace layout (256B-aligned chunks) ----
  char* w = (char*)d_ws;
  auto alloc = [&](size_t bytes) -> char* {
    char* p = w;
    w += (bytes + 255) & ~(size_t)255;
    return p;
  };
  int* flags = (int*)alloc(64);
  // contiguous zero region: cnt, cur, colsum, gstart, gend, pooled
  const int zero_n = NN + NN + DIN + NG + NG + NG * DH;
  int* zreg = (int*)alloc((size_t)zero_n * 4);
  int* cnt = zreg;
  int* cur = cnt + NN;
  float* colsum = (float*)(cur + NN);
  int* gstart = (int*)(colsum + DIN);
  int* gend = gstart + NG;
  float* pooled = (float*)(gend + NG);
  int* rowptr = (int*)alloc((NN + 1) * 4);
  int* bsum = (int*)alloc(SCAN_B * 4);
  int* srcs = (int*)alloc((size_t)NE * 4);
  __hip_bfloat16* xb = (__hip_bfloat16*)alloc((size_t)NN * DIN * 2);
  __hip_bfloat16* aggb = (__hip_bfloat16*)alloc((size_t)NN * DH * 2);
  __hip_bfloat16* hA = (__hip_bfloat16*)alloc((size_t)NN * DH * 2);
  __hip_bfloat16* hB = (__hip_bfloat16*)alloc((size_t)NN * DH * 2);
  __hip_bfloat16* wp1 = (__hip_bfloat16*)alloc((size_t)2 * DIN * DH * 2);
  __hip_bfloat16* wp2 = (__hip_bfloat16*)alloc((size_t)2 * DH * DH * 2);
  float* b1f = (float*)alloc(DH * 4);
  float* b2f = (float*)alloc(DH * 4);

  const int nblk = (NN + SCAN_B - 1) / SCAN_B;       // 196
  const int gemm_grid = (NN + 31) / 32;              // 1563
  const int gat_grid = (NN + 3) / 4;                 // 12500

  k_detect<<<1, 256, 0, stream>>>(x, ei, flags);
  k_zero<<<512, 256, 0, stream>>>(zreg, zero_n);

  // weight packing + fused colsum/convert + handcrafted head
  k_pack_w<<<64, 256, 0, stream>>>(W1r, W1o, b1, wp1, b1f, flags, DIN);
  k_pack_w<<<128, 256, 0, stream>>>(W2r, W2o, b2, wp2, b2f, flags, DH);
  k_prep<<<512, 128, 0, stream>>>(x, xb, colsum, flags);
  k_handcrafted<<<1, 128, 0, stream>>>(colsum, out, flags);

  // CSR build (once; reused by all 3 layers)
  k_deg<<<1024, 256, 0, stream>>>(ei, cnt, flags);
  k_scan1<<<nblk, SCAN_B, 0, stream>>>(cnt, rowptr, bsum);
  k_scan2<<<1, SCAN_B, 0, stream>>>(bsum, nblk);
  k_scan3<<<256, 256, 0, stream>>>(rowptr, bsum);
  k_fill<<<1024, 256, 0, stream>>>(ei, rowptr, cur, srcs, flags);

  // layer 1 (K = 128): xb -> hA
  k_gather128<<<gat_grid, 256, 0, stream>>>(rowptr, srcs, xb, aggb);
  k_gemm<DIN><<<gemm_grid, 256, 0, stream>>>(aggb, xb, wp1, b1f, hA);
  // layer 2 (K = 256): hA -> hB (ping-pong, no aliasing)
  k_gather256<<<gat_grid, 256, 0, stream>>>(rowptr, srcs, hA, aggb);
  k_gemm<DH><<<gemm_grid, 256, 0, stream>>>(aggb, hA, wp2, b2f, hB);
  // layer 3 (K = 256, shared weights): hB -> hA
  k_gather256<<<gat_grid, 256, 0, stream>>>(rowptr, srcs, hB, aggb);
  k_gemm<DH><<<gemm_grid, 256, 0, stream>>>(aggb, hB, wp2, b2f, hA);

  // mean pool: segment bounds (batch sorted) + split partial sums + finalize
  k_bounds<<<nblk, 256, 0, stream>>>(batch, gstart, gend, flags);
  k_poolpart<<<dim3(NG, PSPLIT), 128, 0, stream>>>(gstart, gend, hA, pooled);
  k_poolfin<<<NG, DH, 0, stream>>>(gstart, gend, pooled, out, flags);
}

// Round 9
// 496.924 us; speedup vs baseline: 1.1340x; 1.0207x over previous
//
#include <hip/hip_runtime.h>
#include <hip/hip_bf16.h>
#include <string.h>

#define NN 50000
#define NE 800000
#define DIN 128
#define DH 256
#define NG 64
#define PSPLIT 32

typedef short bf16x8 __attribute__((ext_vector_type(8)));
typedef float f32x4 __attribute__((ext_vector_type(4)));

__device__ __forceinline__ float bf2f(__hip_bfloat16 v) { return __bfloat162float(v); }
__device__ __forceinline__ float bfbits(unsigned int lo16) {
  unsigned int u = lo16 << 16;
  float f;
  memcpy(&f, &u, 4);
  return f;
}
__device__ __forceinline__ unsigned int packbf2(float x, float y) {
  __hip_bfloat16 bx = __float2bfloat16(x), by = __float2bfloat16(y);
  unsigned short ux, uy;
  memcpy(&ux, &bx, 2);
  memcpy(&uy, &by, 2);
  return (unsigned int)ux | ((unsigned int)uy << 16);
}

// flag-driven generic accessors: fbf=1 -> floats stored as bf16; i64=1 -> ints stored as int64
__device__ __forceinline__ float loadF(const void* p, long i, int fbf) {
  return fbf ? bf2f(((const __hip_bfloat16*)p)[i]) : ((const float*)p)[i];
}
__device__ __forceinline__ void storeF(void* p, long i, float v, int fbf) {
  if (fbf) ((__hip_bfloat16*)p)[i] = __float2bfloat16(v);
  else ((float*)p)[i] = v;
}
__device__ __forceinline__ int loadI(const void* p, long i, int i64) {
  return i64 ? (int)((const long long*)p)[i] : ((const int*)p)[i];
}

__global__ void k_detect(const void* x, const void* ei, int* flags) {
  __shared__ int s_f32sig, s_i32sig;
  if (threadIdx.x == 0) { s_f32sig = 0; s_i32sig = 0; }
  __syncthreads();
  int t = threadIdx.x;
  const unsigned short* u = (const unsigned short*)x;
  int f = 0;
  for (int i = 2 * t; i < 8192; i += 512) if (u[i] >= 0x4000) f = 1;
  const unsigned int* w = (const unsigned int*)ei;
  int g = 0;
  for (int i = 2 * t + 1; i < 8192; i += 512) if (w[i] != 0u) g = 1;
  if (f) atomicOr(&s_f32sig, 1);
  if (g) atomicOr(&s_i32sig, 1);
  __syncthreads();
  if (t == 0) { flags[0] = s_f32sig ? 0 : 1; flags[1] = s_i32sig ? 0 : 1; }
}

__global__ void k_zero(int* __restrict__ p, int n) {
  int i = blockIdx.x * blockDim.x + threadIdx.x;
  int stride = gridDim.x * blockDim.x;
  for (; i < n; i += stride) p[i] = 0;
}

// fused colsum + bf16 conversion, vectorized: 16 threads/row, uint4 (8 bf16) per thread.
// block 256 = 16 rows x 16 col-groups; per-thread 8-col f32 partials -> LDS -> 128 atomics.
__global__ __launch_bounds__(256) void k_prep(
    const void* __restrict__ x, __hip_bfloat16* __restrict__ xb,
    float* __restrict__ colsum, const int* __restrict__ flags) {
  int fbf = flags[0];
  int t = threadIdx.x;
  int lane16 = t & 15;   // col group: cols [8*lane16, 8*lane16+8)
  int rowoff = t >> 4;   // 0..15
  float acc[8] = {};
  for (int r = blockIdx.x * 16 + rowoff; r < NN; r += gridDim.x * 16) {
    uint4 o;
    if (fbf) {
      uint4 v = ((const uint4*)x)[(long)r * 16 + lane16];
      acc[0] += bfbits(v.x & 0xffffu); acc[1] += bfbits(v.x >> 16);
      acc[2] += bfbits(v.y & 0xffffu); acc[3] += bfbits(v.y >> 16);
      acc[4] += bfbits(v.z & 0xffffu); acc[5] += bfbits(v.z >> 16);
      acc[6] += bfbits(v.w & 0xffffu); acc[7] += bfbits(v.w >> 16);
      o = v;  // already bf16 bits
    } else {
      float4 a = ((const float4*)x)[(long)r * 32 + lane16 * 2];
      float4 b = ((const float4*)x)[(long)r * 32 + lane16 * 2 + 1];
      acc[0] += a.x; acc[1] += a.y; acc[2] += a.z; acc[3] += a.w;
      acc[4] += b.x; acc[5] += b.y; acc[6] += b.z; acc[7] += b.w;
      o.x = packbf2(a.x, a.y); o.y = packbf2(a.z, a.w);
      o.z = packbf2(b.x, b.y); o.w = packbf2(b.z, b.w);
    }
    ((uint4*)xb)[(long)r * 16 + lane16] = o;
  }
  __shared__ float s[16][DIN];
#pragma unroll
  for (int k = 0; k < 8; ++k) s[rowoff][lane16 * 8 + k] = acc[k];
  __syncthreads();
  if (t < DIN) {
    float v = 0.f;
#pragma unroll
    for (int ro = 0; ro < 16; ++ro) v += s[ro][t];
    atomicAdd(&colsum[t], v);
  }
}

__global__ void k_handcrafted(const float* __restrict__ colsum, void* __restrict__ out,
                              const int* __restrict__ flags) {
  __shared__ float s[DIN];
  int fbf = flags[0];
  int t = threadIdx.x;
  s[t] = colsum[t];
  __syncthreads();
  for (int off = DIN / 2; off > 0; off >>= 1) {
    if (t < off) s[t] += s[t + off];
    __syncthreads();
  }
  float g = s[0];
  storeF(out, NG * DH + t, colsum[t] / g, fbf);
  if (t == 0) storeF(out, NG * DH + DIN, logf(g), fbf);
}

// pack weights into MFMA b-frag order:
// pack[m*K*DH + ((ct*KS + ks)*64 + l)*8 + j] = W_m[(ks*32 + (l>>4)*8 + j)*DH + ct*16 + (l&15)]
__global__ void k_pack_w(const void* __restrict__ Wrel, const void* __restrict__ Wroot,
                         const void* __restrict__ bias, __hip_bfloat16* __restrict__ pack,
                         float* __restrict__ biasf, const int* __restrict__ flags, int K) {
  int fbf = flags[0];
  int KS = K >> 5;
  int total = 2 * K * DH;
  int i = blockIdx.x * blockDim.x + threadIdx.x;
  int stride = gridDim.x * blockDim.x;
  for (int p = i; p < total; p += stride) {
    int m = p / (K * DH);
    int r = p % (K * DH);
    int j = r & 7;
    int l = (r >> 3) & 63;
    int q2 = r >> 9;       // ct*KS + ks
    int ks = q2 % KS;
    int ct = q2 / KS;
    int kk = ks * 32 + (l >> 4) * 8 + j;
    int col = ct * 16 + (l & 15);
    const void* W = m ? Wroot : Wrel;
    pack[p] = __float2bfloat16(loadF(W, (long)kk * DH + col, fbf));
  }
  if (i < DH) biasf[i] = loadF(bias, i, fbf);
}

// ---------- CSR build ----------
__global__ void k_deg(const void* __restrict__ ei, int* __restrict__ cnt,
                      const int* __restrict__ flags) {
  int i64 = flags[1];
  int e = blockIdx.x * blockDim.x + threadIdx.x;
  int stride = gridDim.x * blockDim.x;
  for (; e < NE; e += stride) {
    int d = loadI(ei, (long)NE + e, i64);
    d = min(max(d, 0), NN - 1);
    atomicAdd(&cnt[d], 1);
  }
}

#define SCAN_B 256
__global__ void k_scan1(const int* __restrict__ cnt, int* __restrict__ rowptr,
                        int* __restrict__ bsum) {
  __shared__ int s[SCAN_B];
  int b = blockIdx.x, t = threadIdx.x;
  int i = b * SCAN_B + t;
  int v = (i < NN) ? cnt[i] : 0;
  s[t] = v;
  __syncthreads();
  for (int off = 1; off < SCAN_B; off <<= 1) {
    int xv = (t >= off) ? s[t - off] : 0;
    __syncthreads();
    s[t] += xv;
    __syncthreads();
  }
  if (i < NN) rowptr[i] = s[t] - v;
  if (t == SCAN_B - 1) bsum[b] = s[t];
}

__global__ void k_scan2(int* __restrict__ bsum, int nb) {
  __shared__ int s[SCAN_B];
  int t = threadIdx.x;
  int v = (t < nb) ? bsum[t] : 0;
  s[t] = v;
  __syncthreads();
  for (int off = 1; off < SCAN_B; off <<= 1) {
    int xv = (t >= off) ? s[t - off] : 0;
    __syncthreads();
    s[t] += xv;
    __syncthreads();
  }
  if (t < nb) bsum[t] = s[t] - v;  // exclusive
}

__global__ void k_scan3(int* __restrict__ rowptr, const int* __restrict__ bsum) {
  int i = blockIdx.x * blockDim.x + threadIdx.x;
  int stride = gridDim.x * blockDim.x;
  for (; i < NN; i += stride) rowptr[i] += bsum[i >> 8];
  if (blockIdx.x == 0 && threadIdx.x == 0) rowptr[NN] = NE;
}

__global__ void k_fill(const void* __restrict__ ei, const int* __restrict__ rowptr,
                       int* __restrict__ cur, int* __restrict__ srcs,
                       const int* __restrict__ flags) {
  int i64 = flags[1];
  int e = blockIdx.x * blockDim.x + threadIdx.x;
  int stride = gridDim.x * blockDim.x;
  for (; e < NE; e += stride) {
    int s = loadI(ei, e, i64);
    int d = loadI(ei, (long)NE + e, i64);
    s = min(max(s, 0), NN - 1);
    d = min(max(d, 0), NN - 1);
    int p = atomicAdd(&cur[d], 1);
    srcs[rowptr[d] + p] = s;
  }
}

// ---------- gathers: one wave per node, whole row per wave-instruction ----------
// D=256: lane loads uint2 (8B = 4 bf16); 8 rows in flight per wave
__global__ __launch_bounds__(256) void k_gather256(
    const int* __restrict__ rowptr, const int* __restrict__ srcs,
    const __hip_bfloat16* __restrict__ h, __hip_bfloat16* __restrict__ agg) {
  int node = blockIdx.x * 4 + (threadIdx.x >> 6);
  if (node >= NN) return;
  int lane = threadIdx.x & 63;
  int beg = rowptr[node], end = rowptr[node + 1];
  const uint2* h2 = (const uint2*)h;  // 64 uint2 per row
  float a0 = 0.f, a1 = 0.f, a2 = 0.f, a3 = 0.f;
  int i = beg;
  for (; i + 7 < end; i += 8) {
    uint2 v[8];
#pragma unroll
    for (int u = 0; u < 8; ++u) v[u] = h2[srcs[i + u] * 64 + lane];
#pragma unroll
    for (int u = 0; u < 8; ++u) {
      a0 += bfbits(v[u].x & 0xffffu);
      a1 += bfbits(v[u].x >> 16);
      a2 += bfbits(v[u].y & 0xffffu);
      a3 += bfbits(v[u].y >> 16);
    }
  }
  for (; i < end; ++i) {
    uint2 v0 = h2[srcs[i] * 64 + lane];
    a0 += bfbits(v0.x & 0xffffu);
    a1 += bfbits(v0.x >> 16);
    a2 += bfbits(v0.y & 0xffffu);
    a3 += bfbits(v0.y >> 16);
  }
  uint2 o;
  o.x = packbf2(a0, a1);
  o.y = packbf2(a2, a3);
  ((uint2*)agg)[node * 64 + lane] = o;
}

// D=128: lane loads uint (4B = 2 bf16); 8 rows in flight per wave
__global__ __launch_bounds__(256) void k_gather128(
    const int* __restrict__ rowptr, const int* __restrict__ srcs,
    const __hip_bfloat16* __restrict__ h, __hip_bfloat16* __restrict__ agg) {
  int node = blockIdx.x * 4 + (threadIdx.x >> 6);
  if (node >= NN) return;
  int lane = threadIdx.x & 63;
  int beg = rowptr[node], end = rowptr[node + 1];
  const unsigned int* h2 = (const unsigned int*)h;  // 64 uints per row
  float a0 = 0.f, a1 = 0.f;
  int i = beg;
  for (; i + 7 < end; i += 8) {
    unsigned int v[8];
#pragma unroll
    for (int u = 0; u < 8; ++u) v[u] = h2[srcs[i + u] * 64 + lane];
#pragma unroll
    for (int u = 0; u < 8; ++u) {
      a0 += bfbits(v[u] & 0xffffu);
      a1 += bfbits(v[u] >> 16);
    }
  }
  for (; i < end; ++i) {
    unsigned int v0 = h2[srcs[i] * 64 + lane];
    a0 += bfbits(v0 & 0xffffu);
    a1 += bfbits(v0 >> 16);
  }
  ((unsigned int*)agg)[node * 64 + lane] = packbf2(a0, a1);
}

// out[n][:] = relu(A1[n][:] @ Wrel + A2[n][:] @ Wroot + bias)
// block = 32 rows x 256 cols, 4 waves; wave w = 32x64 tile (mt=2, ct=4), full K unrolled.
template <int K>
__global__ __launch_bounds__(256, 4) void k_gemm(
    const __hip_bfloat16* __restrict__ A1, const __hip_bfloat16* __restrict__ A2,
    const __hip_bfloat16* __restrict__ Wpack, const float* __restrict__ bias,
    __hip_bfloat16* __restrict__ out) {
  constexpr int KS = K >> 5;
  int lane = threadIdx.x & 63;
  int wave = threadIdx.x >> 6;
  int m15 = lane & 15;
  int q = lane >> 4;
  int row0 = blockIdx.x * 32;
  const short* A1s = (const short*)A1;
  const short* A2s = (const short*)A2;
  const short* Wp = (const short*)Wpack;
  const int wrootOfs = K * DH;  // elems: second packed matrix
  f32x4 acc[2][4] = {};
#pragma unroll
  for (int ks = 0; ks < KS; ++ks) {
    int kofs = ks * 32 + q * 8;
    bf16x8 a1[2], a2[2], b1[4], b2[4];
#pragma unroll
    for (int mt = 0; mt < 2; ++mt) {
      int r = row0 + mt * 16 + m15;
      if (r > NN - 1) r = NN - 1;
      a1[mt] = *(const bf16x8*)(A1s + r * K + kofs);
      a2[mt] = *(const bf16x8*)(A2s + r * K + kofs);
    }
#pragma unroll
    for (int ct = 0; ct < 4; ++ct) {
      int gct = wave * 4 + ct;
      const short* base = Wp + ((gct * KS + ks) * 64 + lane) * 8;
      b1[ct] = *(const bf16x8*)(base);
      b2[ct] = *(const bf16x8*)(base + wrootOfs);
    }
#pragma unroll
    for (int mt = 0; mt < 2; ++mt)
#pragma unroll
      for (int ct = 0; ct < 4; ++ct) {
        acc[mt][ct] = __builtin_amdgcn_mfma_f32_16x16x32_bf16(a1[mt], b1[ct], acc[mt][ct], 0, 0, 0);
        acc[mt][ct] = __builtin_amdgcn_mfma_f32_16x16x32_bf16(a2[mt], b2[ct], acc[mt][ct], 0, 0, 0);
      }
  }
#pragma unroll
  for (int mt = 0; mt < 2; ++mt)
#pragma unroll
    for (int ct = 0; ct < 4; ++ct) {
      int col = (wave * 4 + ct) * 16 + m15;
      float bv = bias[col];
#pragma unroll
      for (int r = 0; r < 4; ++r) {
        int row = row0 + mt * 16 + q * 4 + r;
        if (row < NN) {
          float v = acc[mt][ct][r] + bv;
          out[row * DH + col] = __float2bfloat16(fmaxf(v, 0.f));
        }
      }
    }
}

// ---------- pooling (batch is sorted -> segment bounds, no big atomics) ----------
__global__ void k_bounds(const void* __restrict__ batch, int* __restrict__ gstart,
                         int* __restrict__ gend, const int* __restrict__ flags) {
  int i64 = flags[1];
  int n = blockIdx.x * blockDim.x + threadIdx.x;
  if (n >= NN) return;
  int b = min(max(loadI(batch, n, i64), 0), NG - 1);
  int bp = (n == 0) ? -1 : min(max(loadI(batch, n - 1, i64), 0), NG - 1);
  if (b != bp) gstart[b] = n;
  int bn = (n == NN - 1) ? -1 : min(max(loadI(batch, n + 1, i64), 0), NG - 1);
  if (b != bn) gend[b] = n + 1;
}

// grid (NG, PSPLIT), block 128: each block partial-sums a slice of the graph's rows
__global__ void k_poolpart(const int* __restrict__ gstart, const int* __restrict__ gend,
                           const __hip_bfloat16* __restrict__ h, float* __restrict__ pooled) {
  int g = blockIdx.x;
  int p = blockIdx.y;
  int j = threadIdx.x;  // 0..127, 2 cols each
  int s = gstart[g], e = gend[g];
  int len = e - s;
  if (len <= 0) return;
  int chunk = (len + PSPLIT - 1) / PSPLIT;
  int rs = s + p * chunk;
  int re = min(rs + chunk, e);
  if (rs >= re) return;
  const unsigned int* h2 = (const unsigned int*)h;  // 128 uints per row
  float a0 = 0.f, a1 = 0.f;
  for (int r = rs; r < re; ++r) {
    unsigned int v = h2[(long)r * 128 + j];
    a0 += bfbits(v & 0xffffu);
    a1 += bfbits(v >> 16);
  }
  atomicAdd(&pooled[g * DH + 2 * j], a0);
  atomicAdd(&pooled[g * DH + 2 * j + 1], a1);
}

__global__ void k_poolfin(const int* __restrict__ gstart, const int* __restrict__ gend,
                          const float* __restrict__ pooled, void* __restrict__ out,
                          const int* __restrict__ flags) {
  int fbf = flags[0];
  int g = blockIdx.x;
  int j = threadIdx.x;
  float cnt = fmaxf((float)(gend[g] - gstart[g]), 1.0f);
  storeF(out, (long)g * DH + j, pooled[g * DH + j] / cnt, fbf);
}

extern "C" void kernel_launch(void* const* d_in, const int* in_sizes, int n_in,
                              void* d_out, int out_size, void* d_ws, size_t ws_size,
                              hipStream_t stream) {
  const void* x = d_in[0];
  const void* ei = d_in[1];
  const void* batch = d_in[2];
  const void* W1r = d_in[3];
  const void* W1o = d_in[4];
  const void* b1 = d_in[5];
  const void* W2r = d_in[6];
  const void* W2o = d_in[7];
  const void* b2 = d_in[8];
  void* out = d_out;

  // ---- workspace layout (256B-aligned chunks) ----
  char* w = (char*)d_ws;
  auto alloc = [&](size_t bytes) -> char* {
    char* p = w;
    w += (bytes + 255) & ~(size_t)255;
    return p;
  };
  int* flags = (int*)alloc(64);
  // contiguous zero region: cnt, cur, colsum, gstart, gend, pooled
  const int zero_n = NN + NN + DIN + NG + NG + NG * DH;
  int* zreg = (int*)alloc((size_t)zero_n * 4);
  int* cnt = zreg;
  int* cur = cnt + NN;
  float* colsum = (float*)(cur + NN);
  int* gstart = (int*)(colsum + DIN);
  int* gend = gstart + NG;
  float* pooled = (float*)(gend + NG);
  int* rowptr = (int*)alloc((NN + 1) * 4);
  int* bsum = (int*)alloc(SCAN_B * 4);
  int* srcs = (int*)alloc((size_t)NE * 4);
  __hip_bfloat16* xb = (__hip_bfloat16*)alloc((size_t)NN * DIN * 2);
  __hip_bfloat16* aggb = (__hip_bfloat16*)alloc((size_t)NN * DH * 2);
  __hip_bfloat16* hA = (__hip_bfloat16*)alloc((size_t)NN * DH * 2);
  __hip_bfloat16* hB = (__hip_bfloat16*)alloc((size_t)NN * DH * 2);
  __hip_bfloat16* wp1 = (__hip_bfloat16*)alloc((size_t)2 * DIN * DH * 2);
  __hip_bfloat16* wp2 = (__hip_bfloat16*)alloc((size_t)2 * DH * DH * 2);
  float* b1f = (float*)alloc(DH * 4);
  float* b2f = (float*)alloc(DH * 4);

  const int nblk = (NN + SCAN_B - 1) / SCAN_B;       // 196
  const int gemm_grid = (NN + 31) / 32;              // 1563
  const int gat_grid = (NN + 3) / 4;                 // 12500

  k_detect<<<1, 256, 0, stream>>>(x, ei, flags);
  k_zero<<<512, 256, 0, stream>>>(zreg, zero_n);

  // weight packing + fused colsum/convert + handcrafted head
  k_pack_w<<<64, 256, 0, stream>>>(W1r, W1o, b1, wp1, b1f, flags, DIN);
  k_pack_w<<<128, 256, 0, stream>>>(W2r, W2o, b2, wp2, b2f, flags, DH);
  k_prep<<<1024, 256, 0, stream>>>(x, xb, colsum, flags);
  k_handcrafted<<<1, 128, 0, stream>>>(colsum, out, flags);

  // CSR build (once; reused by all 3 layers)
  k_deg<<<1024, 256, 0, stream>>>(ei, cnt, flags);
  k_scan1<<<nblk, SCAN_B, 0, stream>>>(cnt, rowptr, bsum);
  k_scan2<<<1, SCAN_B, 0, stream>>>(bsum, nblk);
  k_scan3<<<256, 256, 0, stream>>>(rowptr, bsum);
  k_fill<<<1024, 256, 0, stream>>>(ei, rowptr, cur, srcs, flags);

  // layer 1 (K = 128): xb -> hA
  k_gather128<<<gat_grid, 256, 0, stream>>>(rowptr, srcs, xb, aggb);
  k_gemm<DIN><<<gemm_grid, 256, 0, stream>>>(aggb, xb, wp1, b1f, hA);
  // layer 2 (K = 256): hA -> hB (ping-pong, no aliasing)
  k_gather256<<<gat_grid, 256, 0, stream>>>(rowptr, srcs, hA, aggb);
  k_gemm<DH><<<gemm_grid, 256, 0, stream>>>(aggb, hA, wp2, b2f, hB);
  // layer 3 (K = 256, shared weights): hB -> hA
  k_gather256<<<gat_grid, 256, 0, stream>>>(rowptr, srcs, hB, aggb);
  k_gemm<DH><<<gemm_grid, 256, 0, stream>>>(aggb, hB, wp2, b2f, hA);

  // mean pool: segment bounds (batch sorted) + split partial sums + finalize
  k_bounds<<<nblk, 256, 0, stream>>>(batch, gstart, gend, flags);
  k_poolpart<<<dim3(NG, PSPLIT), 128, 0, stream>>>(gstart, gend, hA, pooled);
  k_poolfin<<<NG, DH, 0, stream>>>(gstart, gend, pooled, out, flags);
}